// Round 14
// baseline (164.969 us; speedup 1.0000x reference)
//
#include <hip/hip_runtime.h>
#include <cstdint>

// Fused single-head attention, B=4 S=2048 D=1024, fp32 in/out, bf16 MFMA compute.
// Pipeline: cast/pack -> QKV GEMM (v transposed) -> scores+exp GEMM (+row
// partial sums) -> PV GEMM (normalizes by rowsum in epilogue).
// R14 = R13 with the validated BK=128 core applied to qkv and scores too
// (K=1024 -> 8 barrier-pair iterations instead of 16; 64 KB LDS keeps the
// measured 2 blocks/CU). pv unchanged (already BK=128 + XCD-grouped grid).

typedef unsigned short u16;
typedef __attribute__((ext_vector_type(4))) float f32x4;
typedef __attribute__((ext_vector_type(8))) __bf16 bf16x8;

#define AS1(p) ((const __attribute__((address_space(1))) void*)(p))
#define AS3(p) ((__attribute__((address_space(3))) void*)(p))

#define SEQ 2048
#define DM 1024

// ---------- bf16 bit helpers ----------
__device__ __forceinline__ u16 f2b(float f) {
  uint32_t u = __builtin_bit_cast(uint32_t, f);
  u += 0x7FFFu + ((u >> 16) & 1u);   // RNE
  return (u16)(u >> 16);
}
__device__ __forceinline__ float b2f(uint32_t bits16) {
  return __builtin_bit_cast(float, bits16 << 16);
}

// ---------- fused converts: x -> xb, Wq|Wk|Wv -> wcat ----------
__global__ __launch_bounds__(256) void cvt_all(const float* __restrict__ x,
                                               const float* __restrict__ Wq,
                                               const float* __restrict__ Wk,
                                               const float* __restrict__ Wv,
                                               u16* __restrict__ xb,
                                               u16* __restrict__ wcat) {
  const int bid = blockIdx.x;
  const float* src;
  u16* dst;
  int i;
  if (bid < 8192) {                      // x: 8192*1024 fp32
    i = (bid * 256 + threadIdx.x) * 4;
    src = x; dst = xb;
  } else {                               // weights: 3*2^20 fp32
    i = ((bid - 8192) * 256 + threadIdx.x) * 4;
    dst = wcat;
    if (i < (1 << 20))      { src = Wq; }
    else if (i < (2 << 20)) { src = Wk; i -= (1 << 20); dst = wcat + (1 << 20); }
    else                    { src = Wv; i -= (2 << 20); dst = wcat + (2 << 20); }
  }
  float4 v = *(const float4*)(src + i);
  ushort4 o;
  o.x = f2b(v.x); o.y = f2b(v.y); o.z = f2b(v.z); o.w = f2b(v.w);
  *(ushort4*)(dst + i) = o;
}

// ---------- GEMM core BK=128: tiles [128 rows][128 cols] bf16 = 32 KB/op ----------
// Row = 256 B = 16 chunks; swizzle within 8-chunk halves: phys = (lc&8)|((lc&7)^(r&7)).
// Frag reads: lanes l and l+8 hit the same bank at different addrs -> 2-way = free.
// Validated on pv in R13 (dur 50 -> 38 us, 0 conflicts).
__device__ __forceinline__ void stage_tile128(const u16* __restrict__ g, int ld,
                                              char* lds, int tid) {
  int w = tid >> 6;
#pragma unroll
  for (int p = 0; p < 8; ++p) {
    int o  = p * 4096 + w * 1024 + (tid & 63) * 16;
    int r  = o >> 8;                          // 256 B rows
    int pc = (o >> 4) & 15;
    int lc = (pc & 8) | ((pc & 7) ^ (r & 7));
    __builtin_amdgcn_global_load_lds(AS1(g + r * ld + lc * 8),
        AS3(lds + p * 4096 + w * 1024), 16, 0, 0);
  }
}

__device__ __forceinline__ bf16x8 read_frag128(const char* lds, int row, int kk) {
  int lc   = kk >> 3;                         // 0..15
  int phys = (lc & 8) | ((lc & 7) ^ (row & 7));
  return *(const bf16x8*)(lds + row * 256 + phys * 16);
}

__device__ __forceinline__ void gemm_core128(const u16* __restrict__ A,
                                             const u16* __restrict__ Bt,
                                             int K, int lda, int ldb,
                                             char* ldsA, char* ldsB,
                                             f32x4 acc[4][4], int tid) {
  int w = tid >> 6, l = tid & 63;
  int wm = (w >> 1) * 64, wn = (w & 1) * 64;
  int fr = l & 15, fk = (l >> 4) * 8;
  for (int k0 = 0; k0 < K; k0 += 128) {
    stage_tile128(A + k0, lda, ldsA, tid);
    stage_tile128(Bt + k0, ldb, ldsB, tid);
    __syncthreads();
#pragma unroll
    for (int ks = 0; ks < 4; ++ks) {
      bf16x8 af[4], bfr[4];
#pragma unroll
      for (int m = 0; m < 4; ++m) af[m]  = read_frag128(ldsA, wm + m * 16 + fr, ks * 32 + fk);
#pragma unroll
      for (int n = 0; n < 4; ++n) bfr[n] = read_frag128(ldsB, wn + n * 16 + fr, ks * 32 + fk);
#pragma unroll
      for (int m = 0; m < 4; ++m)
#pragma unroll
        for (int n = 0; n < 4; ++n)
          acc[m][n] = __builtin_amdgcn_mfma_f32_16x16x32_bf16(af[m], bfr[n], acc[m][n], 0, 0, 0);
    }
    __syncthreads();
  }
}

#define ZERO_ACC(acc)                                     \
  _Pragma("unroll") for (int m_ = 0; m_ < 4; ++m_)        \
  _Pragma("unroll") for (int n_ = 0; n_ < 4; ++n_)        \
  _Pragma("unroll") for (int j_ = 0; j_ < 4; ++j_)        \
      acc[m_][n_][j_] = 0.f;

// ---------- QKV GEMM: [8192 x 3072] = xb[8192x1024] * wcat[3072x1024]^T + bias ----------
__global__ __launch_bounds__(256, 2) void qkv_gemm(const u16* __restrict__ xb,
                                                   const u16* __restrict__ wcat,
                                                   const float* __restrict__ bq,
                                                   const float* __restrict__ bk,
                                                   const float* __restrict__ bv,
                                                   u16* __restrict__ qb,
                                                   u16* __restrict__ kb,
                                                   u16* __restrict__ vtb) {
  __shared__ __align__(16) char lds[65536];
  int tid = threadIdx.x;
  int bm = blockIdx.y * 128, bn = blockIdx.x * 128;
  f32x4 acc[4][4];
  ZERO_ACC(acc);
  gemm_core128(xb + bm * 1024, wcat + bn * 1024, 1024, 1024, 1024,
               lds, lds + 32768, acc, tid);
  int w = tid >> 6, l = tid & 63;
  int wm = (w >> 1) * 64, wn = (w & 1) * 64;
  int which = bn >> 10;  // uniform per block (128 | 1024)
  if (which == 2) {
    const float* bias = bv;
#pragma unroll
    for (int m = 0; m < 4; ++m)
#pragma unroll
      for (int n = 0; n < 4; ++n) {
        int col = bn + wn + n * 16 + (l & 15);
        int e = col & 1023;
        float bval = bias[e];
#pragma unroll
        for (int j = 0; j < 4; ++j) {
          int row = bm + wm + m * 16 + (l >> 4) * 4 + j;
          int b = row >> 11, s = row & 2047;
          vtb[(b << 21) + e * 2048 + s] = f2b(acc[m][n][j] + bval);
        }
      }
  } else {
    u16* outp = (which == 0) ? qb : kb;
    const float* bias = (which == 0) ? bq : bk;
    const int ebase = bn & 1023;
    __syncthreads();
    // E1: acc -> LDS (chunk-XOR layout)
#pragma unroll
    for (int m = 0; m < 4; ++m)
#pragma unroll
      for (int n = 0; n < 4; ++n) {
        int cl = wn + n * 16 + (l & 15);
        float bval = bias[ebase + cl];
#pragma unroll
        for (int j = 0; j < 4; ++j) {
          int rl = wm + m * 16 + (l >> 4) * 4 + j;
          int chunk = (cl >> 3) ^ (rl & 7);
          *(u16*)(lds + rl * 256 + chunk * 16 + (cl & 7) * 2) = f2b(acc[m][n][j] + bval);
        }
      }
    __syncthreads();
    // E3: row-linear uint4 stores
#pragma unroll
    for (int p = 0; p < 8; ++p) {
      int rl = p * 16 + (tid >> 4);
      int c  = tid & 15;
      int phys = c ^ (rl & 7);
      uint4 v = *(const uint4*)(lds + rl * 256 + phys * 16);
      *(uint4*)(outp + (size_t)(bm + rl) * 1024 + ebase + c * 8) = v;
    }
  }
}

// ---------- scores+exp GEMM per batch: pb = exp(q*k^T/32 - 4), bf16; psum partials ----------
__global__ __launch_bounds__(256, 2) void scores_gemm(const u16* __restrict__ qb,
                                                      const u16* __restrict__ kb,
                                                      u16* __restrict__ pb,
                                                      float* __restrict__ psum) {
  __shared__ __align__(16) char lds[65536];
  int tid = threadIdx.x;
  int b = blockIdx.z;
  int bx = blockIdx.x;
  int bm = blockIdx.y * 128, bn = bx * 128;
  f32x4 acc[4][4];
  ZERO_ACC(acc);
  gemm_core128(qb + b * (SEQ * DM) + bm * 1024,
               kb + b * (SEQ * DM) + bn * 1024, 1024, 1024, 1024,
               lds, lds + 32768, acc, tid);
  u16* out = pb + (size_t)b * SEQ * SEQ;
  int w = tid >> 6, l = tid & 63;
  int wm = (w >> 1) * 64, wn = (w & 1) * 64;
  const int wn_i = w & 1;
#pragma unroll
  for (int m = 0; m < 4; ++m)
#pragma unroll
    for (int n = 0; n < 4; ++n)
#pragma unroll
      for (int j = 0; j < 4; ++j)
        acc[m][n][j] = __expf(acc[m][n][j] * 0.03125f - 4.0f);
#pragma unroll
  for (int m = 0; m < 4; ++m)
#pragma unroll
    for (int j = 0; j < 4; ++j) {
      float ps = (acc[m][0][j] + acc[m][1][j]) + (acc[m][2][j] + acc[m][3][j]);
      ps += __shfl_xor(ps, 1);
      ps += __shfl_xor(ps, 2);
      ps += __shfl_xor(ps, 4);
      ps += __shfl_xor(ps, 8);
      if ((l & 15) == 0) {
        int rl = wm + m * 16 + (l >> 4) * 4 + j;
        psum[((size_t)b * SEQ + bm + rl) * 32 + bx * 2 + wn_i] = ps;
      }
    }
  __syncthreads();
  // E1: bf16(exp) -> LDS (chunk-XOR layout)
#pragma unroll
  for (int m = 0; m < 4; ++m)
#pragma unroll
    for (int n = 0; n < 4; ++n) {
      int cl = wn + n * 16 + (l & 15);
#pragma unroll
      for (int j = 0; j < 4; ++j) {
        int rl = wm + m * 16 + (l >> 4) * 4 + j;
        int chunk = (cl >> 3) ^ (rl & 7);
        *(u16*)(lds + rl * 256 + chunk * 16 + (cl & 7) * 2) = f2b(acc[m][n][j]);
      }
    }
  __syncthreads();
  // E3: row-linear uint4 stores
#pragma unroll
  for (int p = 0; p < 8; ++p) {
    int rl = p * 16 + (tid >> 4);
    int c  = tid & 15;
    int phys = c ^ (rl & 7);
    uint4 v = *(const uint4*)(lds + rl * 256 + phys * 16);
    *(uint4*)(out + (size_t)(bm + rl) * 2048 + bn + c * 8) = v;
  }
}

// ---------- PV GEMM per batch: out = (p~ * v) / rowsum, fp32 out ----------
// BK=128 core; XCD-grouped bm-fastest grid; rowsum in register across gemm,
// inv published via B half of LDS (free after gemm).
__global__ __launch_bounds__(256, 2) void pv_gemm(const u16* __restrict__ pb,
                                                  const u16* __restrict__ vtb,
                                                  const float* __restrict__ psum,
                                                  float* __restrict__ out) {
  __shared__ __align__(16) char lds[65536];
  int tid = threadIdx.x;
  const int lin = blockIdx.x;               // 512 = 8 xcd * 64
  const int wgid = (lin & 7) * 64 + (lin >> 3);
  const int b  = wgid >> 7;
  const int r  = wgid & 127;
  const int bn = (r >> 4) * 128;            // 8 values
  const int bm = (r & 15) * 128;            // 16 values, fastest -> share vtb panel
  float rowsum = 0.f;
  if (tid < 128) {
    const float4* ps = (const float4*)(psum + ((size_t)b * SEQ + bm + tid) * 32);
    float4 s0 = ps[0], s1 = ps[1], s2 = ps[2], s3 = ps[3];
    float4 s4 = ps[4], s5 = ps[5], s6 = ps[6], s7 = ps[7];
    rowsum = ((s0.x + s0.y + s0.z + s0.w) + (s1.x + s1.y + s1.z + s1.w)) +
             ((s2.x + s2.y + s2.z + s2.w) + (s3.x + s3.y + s3.z + s3.w)) +
             ((s4.x + s4.y + s4.z + s4.w) + (s5.x + s5.y + s5.z + s5.w)) +
             ((s6.x + s6.y + s6.z + s6.w) + (s7.x + s7.y + s7.z + s7.w));
  }
  f32x4 acc[4][4];
  ZERO_ACC(acc);
  gemm_core128(pb  + (size_t)b * SEQ * SEQ + bm * 2048,
               vtb + (size_t)b * DM * SEQ  + bn * 2048, 2048, 2048, 2048,
               lds, lds + 32768, acc, tid);
  // publish 1/rowsum via B region (unused during epilogue bounce)
  float* invp = (float*)(lds + 32768);
  if (tid < 128) invp[tid] = 1.0f / rowsum;
  float* o = out + (size_t)b * SEQ * DM;
  int w = tid >> 6, l = tid & 63;
  int wm = (w >> 1) * 64, wn = (w & 1) * 64;
#pragma unroll
  for (int h = 0; h < 2; ++h) {
    __syncthreads();                    // publishes invp (h=0); fences prev pass
#pragma unroll
    for (int mm = 0; mm < 2; ++mm) {
      int m = 2 * h + mm;
#pragma unroll
      for (int n = 0; n < 4; ++n) {
        int cl = wn + n * 16 + (l & 15);
#pragma unroll
        for (int j = 0; j < 4; ++j) {
          int rl = wm + m * 16 + (l >> 4) * 4 + j;
          int sr = (rl & 31) | ((rl >> 6) << 5);          // 0..63
          int clp = cl ^ (((sr >> 2) & 1) << 4);
          *(float*)(lds + sr * 512 + clp * 4) = acc[m][n][j] * invp[rl];
        }
      }
    }
    __syncthreads();
#pragma unroll
    for (int p = 0; p < 8; ++p) {
      int sr  = p * 8 + (tid >> 5);
      int c16 = tid & 31;
      int c16p = c16 ^ (((sr >> 2) & 1) << 2);
      uint4 v = *(const uint4*)(lds + sr * 512 + c16p * 16);
      int grow = (sr & 31) + 32 * h + ((sr >> 5) << 6);
      *(uint4*)(o + (size_t)(bm + grow) * 1024 + bn + c16 * 4) = v;
    }
  }
}

// ---------- launch ----------
extern "C" void kernel_launch(void* const* d_in, const int* in_sizes, int n_in,
                              void* d_out, int out_size, void* d_ws, size_t ws_size,
                              hipStream_t stream) {
  const float* x  = (const float*)d_in[0];
  const float* Wq = (const float*)d_in[1];
  const float* bq = (const float*)d_in[2];
  const float* Wk = (const float*)d_in[3];
  const float* bk = (const float*)d_in[4];
  const float* Wv = (const float*)d_in[5];
  const float* bv = (const float*)d_in[6];
  float* out = (float*)d_out;

  char* ws = (char*)d_ws;
  u16*   xb   = (u16*)(ws);               // 16 MB  bf16 x            [8192][1024]
  u16*   wcat = (u16*)(ws + 16777216);    //  6 MB  bf16 Wq|Wk|Wv     [3072][1024]
  u16*   qb   = (u16*)(ws + 23068672);    // 16 MB  bf16 q            [4][2048][1024]
  u16*   kb   = (u16*)(ws + 39845888);    // 16 MB  bf16 k            [4][2048][1024]
  u16*   vtb  = (u16*)(ws + 56623104);    // 16 MB  bf16 v^T          [4][1024][2048]
  u16*   pb   = (u16*)(ws + 73400320);    // 32 MB  bf16 exp(scores)  [4][2048][2048]
  float* psum = (float*)(ws + 106954752); //  1 MB  fp32 row partials [4][2048][32]

  cvt_all<<<11264, 256, 0, stream>>>(x, Wq, Wk, Wv, xb, wcat);
  qkv_gemm<<<dim3(24, 64), 256, 0, stream>>>(xb, wcat, bq, bk, bv, qb, kb, vtb);
  scores_gemm<<<dim3(16, 16, 4), 256, 0, stream>>>(qb, kb, pb, psum);
  pv_gemm<<<512, 256, 0, stream>>>(pb, vtb, psum, out);
}

// Round 15
// 152.574 us; speedup vs baseline: 1.0812x; 1.0812x over previous
//
#include <hip/hip_runtime.h>
#include <cstdint>

// Fused single-head attention, B=4 S=2048 D=1024, fp32 in/out, bf16 MFMA compute.
// Pipeline: cast/pack -> QKV GEMM (v transposed) -> scores+exp GEMM (+row
// partial sums) -> PV GEMM (normalizes by rowsum in epilogue).
// R15 = R13 (best measured: 157.1us) with ONE change: scores gets the
// XCD-grouped bm-fastest 1D grid (validated on pv in R13). qkv/scores use the
// BK=64 core (BK=128 on K=1024 measured -11%: +6.3M conflicts, occ 28->18%,
// R14); pv keeps BK=128 + XCD grid (K=2048: barrier savings dominate).

typedef unsigned short u16;
typedef __attribute__((ext_vector_type(4))) float f32x4;
typedef __attribute__((ext_vector_type(8))) __bf16 bf16x8;

#define AS1(p) ((const __attribute__((address_space(1))) void*)(p))
#define AS3(p) ((__attribute__((address_space(3))) void*)(p))

#define SEQ 2048
#define DM 1024

// ---------- bf16 bit helpers ----------
__device__ __forceinline__ u16 f2b(float f) {
  uint32_t u = __builtin_bit_cast(uint32_t, f);
  u += 0x7FFFu + ((u >> 16) & 1u);   // RNE
  return (u16)(u >> 16);
}
__device__ __forceinline__ float b2f(uint32_t bits16) {
  return __builtin_bit_cast(float, bits16 << 16);
}

// ---------- fused converts: x -> xb, Wq|Wk|Wv -> wcat ----------
__global__ __launch_bounds__(256) void cvt_all(const float* __restrict__ x,
                                               const float* __restrict__ Wq,
                                               const float* __restrict__ Wk,
                                               const float* __restrict__ Wv,
                                               u16* __restrict__ xb,
                                               u16* __restrict__ wcat) {
  const int bid = blockIdx.x;
  const float* src;
  u16* dst;
  int i;
  if (bid < 8192) {                      // x: 8192*1024 fp32
    i = (bid * 256 + threadIdx.x) * 4;
    src = x; dst = xb;
  } else {                               // weights: 3*2^20 fp32
    i = ((bid - 8192) * 256 + threadIdx.x) * 4;
    dst = wcat;
    if (i < (1 << 20))      { src = Wq; }
    else if (i < (2 << 20)) { src = Wk; i -= (1 << 20); dst = wcat + (1 << 20); }
    else                    { src = Wv; i -= (2 << 20); dst = wcat + (2 << 20); }
  }
  float4 v = *(const float4*)(src + i);
  ushort4 o;
  o.x = f2b(v.x); o.y = f2b(v.y); o.z = f2b(v.z); o.w = f2b(v.w);
  *(ushort4*)(dst + i) = o;
}

// ---------- GEMM core BK=64 (R1/R10 verbatim; 0 conflicts measured) ----------
#define BK 64

__device__ __forceinline__ void stage_tile(const u16* __restrict__ g, int ld,
                                           char* lds, int tid) {
  int w = tid >> 6, l = tid & 63;
#pragma unroll
  for (int p = 0; p < 4; ++p) {
    int o  = p * 4096 + w * 1024 + l * 16;   // linear LDS byte offset
    int r  = o >> 7;                          // row (128B per row)
    int pc = (o >> 4) & 7;                    // physical 16B chunk
    int lc = pc ^ (r & 7);                    // logical chunk to fetch
    const u16* src = g + r * ld + lc * 8;
    char* dst = lds + p * 4096 + w * 1024;    // wave-uniform base; HW adds lane*16
    __builtin_amdgcn_global_load_lds(AS1(src), AS3(dst), 16, 0, 0);
  }
}

__device__ __forceinline__ bf16x8 read_frag(const char* lds, int row, int kk) {
  int lc  = kk >> 3;
  int off = row * 128 + ((lc ^ (row & 7)) << 4);
  return *(const bf16x8*)(lds + off);
}

__device__ __forceinline__ void gemm_core(const u16* __restrict__ A,
                                          const u16* __restrict__ Bt,
                                          int K, int lda, int ldb,
                                          char* ldsA, char* ldsB,
                                          f32x4 acc[4][4], int tid) {
  int w = tid >> 6, l = tid & 63;
  int wm = (w >> 1) * 64, wn = (w & 1) * 64;
  int fr = l & 15, fk = (l >> 4) * 8;
  for (int k0 = 0; k0 < K; k0 += BK) {
    stage_tile(A + k0, lda, ldsA, tid);
    stage_tile(Bt + k0, ldb, ldsB, tid);
    __syncthreads();
#pragma unroll
    for (int ks = 0; ks < 2; ++ks) {
      bf16x8 af[4], bfr[4];
#pragma unroll
      for (int m = 0; m < 4; ++m) af[m]  = read_frag(ldsA, wm + m * 16 + fr, ks * 32 + fk);
#pragma unroll
      for (int n = 0; n < 4; ++n) bfr[n] = read_frag(ldsB, wn + n * 16 + fr, ks * 32 + fk);
#pragma unroll
      for (int m = 0; m < 4; ++m)
#pragma unroll
        for (int n = 0; n < 4; ++n)
          acc[m][n] = __builtin_amdgcn_mfma_f32_16x16x32_bf16(af[m], bfr[n], acc[m][n], 0, 0, 0);
    }
    __syncthreads();
  }
}

// ---------- GEMM core BK=128 (pv only; K=2048) ----------
__device__ __forceinline__ void stage_tile128(const u16* __restrict__ g, int ld,
                                              char* lds, int tid) {
  int w = tid >> 6;
#pragma unroll
  for (int p = 0; p < 8; ++p) {
    int o  = p * 4096 + w * 1024 + (tid & 63) * 16;
    int r  = o >> 8;                          // 256 B rows
    int pc = (o >> 4) & 15;
    int lc = (pc & 8) | ((pc & 7) ^ (r & 7));
    __builtin_amdgcn_global_load_lds(AS1(g + r * ld + lc * 8),
        AS3(lds + p * 4096 + w * 1024), 16, 0, 0);
  }
}

__device__ __forceinline__ bf16x8 read_frag128(const char* lds, int row, int kk) {
  int lc   = kk >> 3;                         // 0..15
  int phys = (lc & 8) | ((lc & 7) ^ (row & 7));
  return *(const bf16x8*)(lds + row * 256 + phys * 16);
}

__device__ __forceinline__ void gemm_core128(const u16* __restrict__ A,
                                             const u16* __restrict__ Bt,
                                             int K, int lda, int ldb,
                                             char* ldsA, char* ldsB,
                                             f32x4 acc[4][4], int tid) {
  int w = tid >> 6, l = tid & 63;
  int wm = (w >> 1) * 64, wn = (w & 1) * 64;
  int fr = l & 15, fk = (l >> 4) * 8;
  for (int k0 = 0; k0 < K; k0 += 128) {
    stage_tile128(A + k0, lda, ldsA, tid);
    stage_tile128(Bt + k0, ldb, ldsB, tid);
    __syncthreads();
#pragma unroll
    for (int ks = 0; ks < 4; ++ks) {
      bf16x8 af[4], bfr[4];
#pragma unroll
      for (int m = 0; m < 4; ++m) af[m]  = read_frag128(ldsA, wm + m * 16 + fr, ks * 32 + fk);
#pragma unroll
      for (int n = 0; n < 4; ++n) bfr[n] = read_frag128(ldsB, wn + n * 16 + fr, ks * 32 + fk);
#pragma unroll
      for (int m = 0; m < 4; ++m)
#pragma unroll
        for (int n = 0; n < 4; ++n)
          acc[m][n] = __builtin_amdgcn_mfma_f32_16x16x32_bf16(af[m], bfr[n], acc[m][n], 0, 0, 0);
    }
    __syncthreads();
  }
}

#define ZERO_ACC(acc)                                     \
  _Pragma("unroll") for (int m_ = 0; m_ < 4; ++m_)        \
  _Pragma("unroll") for (int n_ = 0; n_ < 4; ++n_)        \
  _Pragma("unroll") for (int j_ = 0; j_ < 4; ++j_)        \
      acc[m_][n_][j_] = 0.f;

// ---------- QKV GEMM: [8192 x 3072] = xb[8192x1024] * wcat[3072x1024]^T + bias ----------
__global__ __launch_bounds__(256, 2) void qkv_gemm(const u16* __restrict__ xb,
                                                   const u16* __restrict__ wcat,
                                                   const float* __restrict__ bq,
                                                   const float* __restrict__ bk,
                                                   const float* __restrict__ bv,
                                                   u16* __restrict__ qb,
                                                   u16* __restrict__ kb,
                                                   u16* __restrict__ vtb) {
  __shared__ __align__(16) char lds[32768];
  int tid = threadIdx.x;
  int bm = blockIdx.y * 128, bn = blockIdx.x * 128;
  f32x4 acc[4][4];
  ZERO_ACC(acc);
  gemm_core(xb + bm * 1024, wcat + bn * 1024, 1024, 1024, 1024,
            lds, lds + 16384, acc, tid);
  int w = tid >> 6, l = tid & 63;
  int wm = (w >> 1) * 64, wn = (w & 1) * 64;
  int which = bn >> 10;  // uniform per block (128 | 1024)
  if (which == 2) {
    const float* bias = bv;
#pragma unroll
    for (int m = 0; m < 4; ++m)
#pragma unroll
      for (int n = 0; n < 4; ++n) {
        int col = bn + wn + n * 16 + (l & 15);
        int e = col & 1023;
        float bval = bias[e];
#pragma unroll
        for (int j = 0; j < 4; ++j) {
          int row = bm + wm + m * 16 + (l >> 4) * 4 + j;
          int b = row >> 11, s = row & 2047;
          vtb[(b << 21) + e * 2048 + s] = f2b(acc[m][n][j] + bval);
        }
      }
  } else {
    u16* outp = (which == 0) ? qb : kb;
    const float* bias = (which == 0) ? bq : bk;
    const int ebase = bn & 1023;
    __syncthreads();
    // E1: acc -> LDS (chunk-XOR layout)
#pragma unroll
    for (int m = 0; m < 4; ++m)
#pragma unroll
      for (int n = 0; n < 4; ++n) {
        int cl = wn + n * 16 + (l & 15);
        float bval = bias[ebase + cl];
#pragma unroll
        for (int j = 0; j < 4; ++j) {
          int rl = wm + m * 16 + (l >> 4) * 4 + j;
          int chunk = (cl >> 3) ^ (rl & 7);
          *(u16*)(lds + rl * 256 + chunk * 16 + (cl & 7) * 2) = f2b(acc[m][n][j] + bval);
        }
      }
    __syncthreads();
    // E3: row-linear uint4 stores
#pragma unroll
    for (int p = 0; p < 8; ++p) {
      int rl = p * 16 + (tid >> 4);
      int c  = tid & 15;
      int phys = c ^ (rl & 7);
      uint4 v = *(const uint4*)(lds + rl * 256 + phys * 16);
      *(uint4*)(outp + (size_t)(bm + rl) * 1024 + ebase + c * 8) = v;
    }
  }
}

// ---------- scores+exp GEMM per batch: pb = exp(q*k^T/32 - 4), bf16; psum partials ----------
// XCD-grouped bm-fastest 1D grid: 1024 = 8 xcd * 128.
__global__ __launch_bounds__(256, 2) void scores_gemm(const u16* __restrict__ qb,
                                                      const u16* __restrict__ kb,
                                                      u16* __restrict__ pb,
                                                      float* __restrict__ psum) {
  __shared__ __align__(16) char lds[32768];
  int tid = threadIdx.x;
  const int lin = blockIdx.x;
  const int wgid = (lin & 7) * 128 + (lin >> 3);
  const int b  = wgid >> 8;
  const int r  = wgid & 255;
  const int bn = (r >> 4) * 128;            // 16 values
  const int bm = (r & 15) * 128;            // 16 values, fastest -> share kb panel
  const int bx = bn >> 7;
  f32x4 acc[4][4];
  ZERO_ACC(acc);
  gemm_core(qb + b * (SEQ * DM) + bm * 1024,
            kb + b * (SEQ * DM) + bn * 1024, 1024, 1024, 1024,
            lds, lds + 16384, acc, tid);
  u16* out = pb + (size_t)b * SEQ * SEQ;
  int w = tid >> 6, l = tid & 63;
  int wm = (w >> 1) * 64, wn = (w & 1) * 64;
  const int wn_i = w & 1;
#pragma unroll
  for (int m = 0; m < 4; ++m)
#pragma unroll
    for (int n = 0; n < 4; ++n)
#pragma unroll
      for (int j = 0; j < 4; ++j)
        acc[m][n][j] = __expf(acc[m][n][j] * 0.03125f - 4.0f);
#pragma unroll
  for (int m = 0; m < 4; ++m)
#pragma unroll
    for (int j = 0; j < 4; ++j) {
      float ps = (acc[m][0][j] + acc[m][1][j]) + (acc[m][2][j] + acc[m][3][j]);
      ps += __shfl_xor(ps, 1);
      ps += __shfl_xor(ps, 2);
      ps += __shfl_xor(ps, 4);
      ps += __shfl_xor(ps, 8);
      if ((l & 15) == 0) {
        int rl = wm + m * 16 + (l >> 4) * 4 + j;
        psum[((size_t)b * SEQ + bm + rl) * 32 + bx * 2 + wn_i] = ps;
      }
    }
  __syncthreads();
  // E1: bf16(exp) -> LDS (chunk-XOR layout)
#pragma unroll
  for (int m = 0; m < 4; ++m)
#pragma unroll
    for (int n = 0; n < 4; ++n) {
      int cl = wn + n * 16 + (l & 15);
#pragma unroll
      for (int j = 0; j < 4; ++j) {
        int rl = wm + m * 16 + (l >> 4) * 4 + j;
        int chunk = (cl >> 3) ^ (rl & 7);
        *(u16*)(lds + rl * 256 + chunk * 16 + (cl & 7) * 2) = f2b(acc[m][n][j]);
      }
    }
  __syncthreads();
  // E3: row-linear uint4 stores
#pragma unroll
  for (int p = 0; p < 8; ++p) {
    int rl = p * 16 + (tid >> 4);
    int c  = tid & 15;
    int phys = c ^ (rl & 7);
    uint4 v = *(const uint4*)(lds + rl * 256 + phys * 16);
    *(uint4*)(out + (size_t)(bm + rl) * 2048 + bn + c * 8) = v;
  }
}

// ---------- PV GEMM per batch: out = (p~ * v) / rowsum, fp32 out ----------
// BK=128 core; XCD-grouped bm-fastest grid; rowsum in register across gemm,
// inv published via B half of LDS (free after gemm).
__global__ __launch_bounds__(256, 2) void pv_gemm(const u16* __restrict__ pb,
                                                  const u16* __restrict__ vtb,
                                                  const float* __restrict__ psum,
                                                  float* __restrict__ out) {
  __shared__ __align__(16) char lds[65536];
  int tid = threadIdx.x;
  const int lin = blockIdx.x;               // 512 = 8 xcd * 64
  const int wgid = (lin & 7) * 64 + (lin >> 3);
  const int b  = wgid >> 7;
  const int r  = wgid & 127;
  const int bn = (r >> 4) * 128;            // 8 values
  const int bm = (r & 15) * 128;            // 16 values, fastest -> share vtb panel
  float rowsum = 0.f;
  if (tid < 128) {
    const float4* ps = (const float4*)(psum + ((size_t)b * SEQ + bm + tid) * 32);
    float4 s0 = ps[0], s1 = ps[1], s2 = ps[2], s3 = ps[3];
    float4 s4 = ps[4], s5 = ps[5], s6 = ps[6], s7 = ps[7];
    rowsum = ((s0.x + s0.y + s0.z + s0.w) + (s1.x + s1.y + s1.z + s1.w)) +
             ((s2.x + s2.y + s2.z + s2.w) + (s3.x + s3.y + s3.z + s3.w)) +
             ((s4.x + s4.y + s4.z + s4.w) + (s5.x + s5.y + s5.z + s5.w)) +
             ((s6.x + s6.y + s6.z + s6.w) + (s7.x + s7.y + s7.z + s7.w));
  }
  f32x4 acc[4][4];
  ZERO_ACC(acc);
  gemm_core128(pb  + (size_t)b * SEQ * SEQ + bm * 2048,
               vtb + (size_t)b * DM * SEQ  + bn * 2048, 2048, 2048, 2048,
               lds, lds + 32768, acc, tid);
  // publish 1/rowsum via B region (unused during epilogue bounce)
  float* invp = (float*)(lds + 32768);
  if (tid < 128) invp[tid] = 1.0f / rowsum;
  float* o = out + (size_t)b * SEQ * DM;
  int w = tid >> 6, l = tid & 63;
  int wm = (w >> 1) * 64, wn = (w & 1) * 64;
#pragma unroll
  for (int h = 0; h < 2; ++h) {
    __syncthreads();                    // publishes invp (h=0); fences prev pass
#pragma unroll
    for (int mm = 0; mm < 2; ++mm) {
      int m = 2 * h + mm;
#pragma unroll
      for (int n = 0; n < 4; ++n) {
        int cl = wn + n * 16 + (l & 15);
#pragma unroll
        for (int j = 0; j < 4; ++j) {
          int rl = wm + m * 16 + (l >> 4) * 4 + j;
          int sr = (rl & 31) | ((rl >> 6) << 5);          // 0..63
          int clp = cl ^ (((sr >> 2) & 1) << 4);
          *(float*)(lds + sr * 512 + clp * 4) = acc[m][n][j] * invp[rl];
        }
      }
    }
    __syncthreads();
#pragma unroll
    for (int p = 0; p < 8; ++p) {
      int sr  = p * 8 + (tid >> 5);
      int c16 = tid & 31;
      int c16p = c16 ^ (((sr >> 2) & 1) << 2);
      uint4 v = *(const uint4*)(lds + sr * 512 + c16p * 16);
      int grow = (sr & 31) + 32 * h + ((sr >> 5) << 6);
      *(uint4*)(o + (size_t)(bm + grow) * 1024 + bn + c16 * 4) = v;
    }
  }
}

// ---------- launch ----------
extern "C" void kernel_launch(void* const* d_in, const int* in_sizes, int n_in,
                              void* d_out, int out_size, void* d_ws, size_t ws_size,
                              hipStream_t stream) {
  const float* x  = (const float*)d_in[0];
  const float* Wq = (const float*)d_in[1];
  const float* bq = (const float*)d_in[2];
  const float* Wk = (const float*)d_in[3];
  const float* bk = (const float*)d_in[4];
  const float* Wv = (const float*)d_in[5];
  const float* bv = (const float*)d_in[6];
  float* out = (float*)d_out;

  char* ws = (char*)d_ws;
  u16*   xb   = (u16*)(ws);               // 16 MB  bf16 x            [8192][1024]
  u16*   wcat = (u16*)(ws + 16777216);    //  6 MB  bf16 Wq|Wk|Wv     [3072][1024]
  u16*   qb   = (u16*)(ws + 23068672);    // 16 MB  bf16 q            [4][2048][1024]
  u16*   kb   = (u16*)(ws + 39845888);    // 16 MB  bf16 k            [4][2048][1024]
  u16*   vtb  = (u16*)(ws + 56623104);    // 16 MB  bf16 v^T          [4][1024][2048]
  u16*   pb   = (u16*)(ws + 73400320);    // 32 MB  bf16 exp(scores)  [4][2048][2048]
  float* psum = (float*)(ws + 106954752); //  1 MB  fp32 row partials [4][2048][32]

  cvt_all<<<11264, 256, 0, stream>>>(x, Wq, Wk, Wv, xb, wcat);
  qkv_gemm<<<dim3(24, 64), 256, 0, stream>>>(xb, wcat, bq, bk, bv, qb, kb, vtb);
  scores_gemm<<<1024, 256, 0, stream>>>(qb, kb, pb, psum);
  pv_gemm<<<512, 256, 0, stream>>>(pb, vtb, psum, out);
}